// Round 8
// baseline (567.296 us; speedup 1.0000x reference)
//
#include <hip/hip_runtime.h>
#include <hip/hip_bf16.h>

#define N_NODES 50000
#define N_EDGES 800000
#define IN_CH 1024
#define OUT_CH 256
#define NBLK 196  // ceil(N_NODES/256)

typedef __attribute__((ext_vector_type(8))) short bf16x8;
typedef __attribute__((ext_vector_type(4))) float f32x4;

__device__ inline unsigned short f2bf(float f) {
  union { float f; unsigned int u; } v; v.f = f;
  unsigned int r = v.u + 0x7fffu + ((v.u >> 16) & 1u);
  return (unsigned short)(r >> 16);
}
__device__ inline float bf2f(unsigned short u) {
  union { unsigned int u; float f; } v; v.u = ((unsigned int)u) << 16;
  return v.f;
}
// pack two f32 -> two bf16 in one u32 (lo = a, hi = b), RNE
__device__ inline unsigned int cvtpk_bf16(float a, float b) {
  unsigned int r;
  asm("v_cvt_pk_bf16_f32 %0, %1, %2" : "=v"(r) : "v"(a), "v"(b));
  return r;
}

// blocks [0,256): convert W fp32 -> bf16; blocks [256,...): histogram of tar
__global__ __launch_bounds__(256) void prep_hist(const float* __restrict__ W,
                                                 unsigned short* __restrict__ Wb,
                                                 const int* __restrict__ tar,
                                                 int* __restrict__ counts) {
  const int b = blockIdx.x, t = threadIdx.x;
  if (b < 256) {
    const int i4 = (b * 256 + t) * 4;
    float4 f = *(const float4*)(W + i4);
    *(ushort4*)(Wb + i4) = make_ushort4(f2bf(f.x), f2bf(f.y), f2bf(f.z), f2bf(f.w));
  } else {
    const int e = (b - 256) * 256 + t;
    if (e < N_EDGES) atomicAdd(&counts[tar[e]], 1);
  }
}

// Hb[m][n] = bf16( sum_k X[m][k]*W[n][k] + b[n] )
// Tall-skinny structure: W-slice (64 cols) lives in LDS (two 64KB K-chunks,
// 3 barriers/block TOTAL); A streams global->registers (no LDS, no barriers
// in the K-loop). Wave = 32 rows x 64 cols; per step: 4 glb + 4 ds + 8 MFMA.
// Grid (391, 4); 64KB LDS -> 2 blocks/CU.
__global__ __launch_bounds__(256, 2) void gemm_proj(
    const float* __restrict__ X, const unsigned short* __restrict__ Wb,
    const float* __restrict__ bias, unsigned short* __restrict__ Hb)
{
  __shared__ unsigned short lds_w[64][512];  // 64 KB, 16B-chunk XOR swizzle

  const int tid  = threadIdx.x;
  const int lane = tid & 63;
  const int wv   = tid >> 6;        // 0..3
  const int l15  = lane & 15;
  const int hi   = lane >> 4;       // 0..3
  const int m0   = blockIdx.x * 128;
  const int n0   = blockIdx.y * 64; // N-slice

  f32x4 acc[2][4];
  #pragma unroll
  for (int f = 0; f < 2; f++)
    #pragma unroll
    for (int j = 0; j < 4; j++) acc[f][j] = (f32x4)0.0f;

  // this wave's two A-frag row sets
  const int r0 = m0 + wv * 32 + l15;
  const int r1 = r0 + 16;
  const bool ok0 = r0 < N_NODES, ok1 = r1 < N_NODES;
  const float* xa0 = X + (size_t)r0 * IN_CH + hi * 8;
  const float* xa1 = X + (size_t)r1 * IN_CH + hi * 8;
  const float4 fz = make_float4(0.f, 0.f, 0.f, 0.f);

  for (int kc = 0; kc < 2; kc++) {
    // ---- stage W chunk: rows n0..n0+64, k in [kc*512, kc*512+512) ----
    if (kc) __syncthreads();  // all reads of previous chunk complete
    #pragma unroll
    for (int it = 0; it < 16; it++) {
      const int idx = it * 256 + tid;   // 0..4095 16B-chunks
      const int n   = idx >> 6;         // 0..63
      const int c   = idx & 63;         // chunk within row
      const int pc  = c ^ (n & 7);      // XOR swizzle (2-way on read = free)
      const bf16x8 v =
          *(const bf16x8*)(Wb + (size_t)(n0 + n) * IN_CH + kc * 512 + c * 8);
      *(bf16x8*)&lds_w[n][pc * 8] = v;
    }
    __syncthreads();

    // ---- barrier-free K streaming: 16 steps of K=32 ----
    const int kbase = kc * 512;
    float4 nA0a, nA0b, nA1a, nA1b;
    nA0a = ok0 ? *(const float4*)(xa0 + kbase)     : fz;
    nA0b = ok0 ? *(const float4*)(xa0 + kbase + 4) : fz;
    nA1a = ok1 ? *(const float4*)(xa1 + kbase)     : fz;
    nA1b = ok1 ? *(const float4*)(xa1 + kbase + 4) : fz;

    #pragma unroll
    for (int ks = 0; ks < 16; ks++) {
      const float4 cA0a = nA0a, cA0b = nA0b, cA1a = nA1a, cA1b = nA1b;
      if (ks + 1 < 16) {
        const int ko = kbase + (ks + 1) * 32;
        nA0a = ok0 ? *(const float4*)(xa0 + ko)     : fz;
        nA0b = ok0 ? *(const float4*)(xa0 + ko + 4) : fz;
        nA1a = ok1 ? *(const float4*)(xa1 + ko)     : fz;
        nA1b = ok1 ? *(const float4*)(xa1 + ko + 4) : fz;
      }
      // B-frags: n = 16j + l15; chunk c = ks*4 + hi; phys = c ^ (l15&7)
      const int pc = ((ks << 2) + hi) ^ (l15 & 7);
      const bf16x8 bf0 = *(const bf16x8*)&lds_w[l15][pc * 8];
      const bf16x8 bf1 = *(const bf16x8*)&lds_w[16 + l15][pc * 8];
      const bf16x8 bf2 = *(const bf16x8*)&lds_w[32 + l15][pc * 8];
      const bf16x8 bf3 = *(const bf16x8*)&lds_w[48 + l15][pc * 8];
      // A-frags fp32 -> bf16
      union { unsigned int u[4]; bf16x8 v; } t0, t1;
      t0.u[0] = cvtpk_bf16(cA0a.x, cA0a.y);
      t0.u[1] = cvtpk_bf16(cA0a.z, cA0a.w);
      t0.u[2] = cvtpk_bf16(cA0b.x, cA0b.y);
      t0.u[3] = cvtpk_bf16(cA0b.z, cA0b.w);
      t1.u[0] = cvtpk_bf16(cA1a.x, cA1a.y);
      t1.u[1] = cvtpk_bf16(cA1a.z, cA1a.w);
      t1.u[2] = cvtpk_bf16(cA1b.x, cA1b.y);
      t1.u[3] = cvtpk_bf16(cA1b.z, cA1b.w);
      acc[0][0] = __builtin_amdgcn_mfma_f32_16x16x32_bf16(t0.v, bf0, acc[0][0], 0, 0, 0);
      acc[0][1] = __builtin_amdgcn_mfma_f32_16x16x32_bf16(t0.v, bf1, acc[0][1], 0, 0, 0);
      acc[0][2] = __builtin_amdgcn_mfma_f32_16x16x32_bf16(t0.v, bf2, acc[0][2], 0, 0, 0);
      acc[0][3] = __builtin_amdgcn_mfma_f32_16x16x32_bf16(t0.v, bf3, acc[0][3], 0, 0, 0);
      acc[1][0] = __builtin_amdgcn_mfma_f32_16x16x32_bf16(t1.v, bf0, acc[1][0], 0, 0, 0);
      acc[1][1] = __builtin_amdgcn_mfma_f32_16x16x32_bf16(t1.v, bf1, acc[1][1], 0, 0, 0);
      acc[1][2] = __builtin_amdgcn_mfma_f32_16x16x32_bf16(t1.v, bf2, acc[1][2], 0, 0, 0);
      acc[1][3] = __builtin_amdgcn_mfma_f32_16x16x32_bf16(t1.v, bf3, acc[1][3], 0, 0, 0);
    }
  }

  // epilogue: C/D layout col = lane&15, row = hi*4 + r (within frag)
  float bj[4];
  #pragma unroll
  for (int j = 0; j < 4; j++) bj[j] = bias[n0 + 16 * j + l15];

  #pragma unroll
  for (int f = 0; f < 2; f++) {
    const int grow_base = m0 + wv * 32 + f * 16 + hi * 4;
    #pragma unroll
    for (int r = 0; r < 4; r++) {
      const int grow = grow_base + r;
      if (grow < N_NODES) {
        #pragma unroll
        for (int j = 0; j < 4; j++) {
          const int gcol = n0 + 16 * j + l15;
          Hb[(size_t)grow * OUT_CH + gcol] = f2bf(acc[f][j][r] + bj[j]);
        }
      }
    }
  }
}

// per-block exclusive scan; local-excl to offsets, block total to blocksum
__global__ __launch_bounds__(256) void scan_block(const int* __restrict__ counts,
                                                  int* __restrict__ offsets,
                                                  int* __restrict__ blocksum) {
  __shared__ int wsum[4];
  const int tid = threadIdx.x, lane = tid & 63, wv = tid >> 6;
  const int i = blockIdx.x * 256 + tid;
  const int v = (i < N_NODES) ? counts[i] : 0;
  int s = v;
  #pragma unroll
  for (int off = 1; off < 64; off <<= 1) {
    int t = __shfl_up(s, off, 64);
    if (lane >= off) s += t;
  }
  if (lane == 63) wsum[wv] = s;
  __syncthreads();
  if (tid == 0) {
    int c = 0;
    #pragma unroll
    for (int k = 0; k < 4; k++) { int t = wsum[k]; wsum[k] = c; c += t; }
  }
  __syncthreads();
  const int excl = wsum[wv] + s - v;
  if (i < N_NODES) offsets[i] = excl;
  if (tid == 255) blocksum[blockIdx.x] = excl + v;
}

__global__ __launch_bounds__(256) void scan_sums(int* __restrict__ blocksum,
                                                 int* __restrict__ offsets) {
  __shared__ int wsum[4];
  const int tid = threadIdx.x, lane = tid & 63, wv = tid >> 6;
  const int v = (tid < NBLK) ? blocksum[tid] : 0;
  int s = v;
  #pragma unroll
  for (int off = 1; off < 64; off <<= 1) {
    int t = __shfl_up(s, off, 64);
    if (lane >= off) s += t;
  }
  if (lane == 63) wsum[wv] = s;
  __syncthreads();
  if (tid == 0) {
    int c = 0;
    #pragma unroll
    for (int k = 0; k < 4; k++) { int t = wsum[k]; wsum[k] = c; c += t; }
  }
  __syncthreads();
  const int excl = wsum[wv] + s - v;
  if (tid < NBLK) blocksum[tid] = excl;
  if (tid == 255) offsets[N_NODES] = excl;
}

__global__ __launch_bounds__(256) void finalize_offsets(int* __restrict__ offsets,
                                                        const int* __restrict__ blocksum,
                                                        int* __restrict__ cursor) {
  const int i = blockIdx.x * 256 + threadIdx.x;
  if (i < N_NODES) {
    const int off = offsets[i] + blocksum[i >> 8];
    offsets[i] = off;
    cursor[i] = off;
  }
}

__global__ __launch_bounds__(256) void fill_csr(const int* __restrict__ src,
                                                const int* __restrict__ tar,
                                                const float* __restrict__ ew,
                                                int* __restrict__ cursor,
                                                int2* __restrict__ edata) {
  int e = blockIdx.x * blockDim.x + threadIdx.x;
  if (e >= N_EDGES) return;
  const int t = tar[e];
  const int p = atomicAdd(&cursor[t], 1);
  edata[p] = make_int2(src[e], __float_as_int(ew[e]));
}

// one wave per node: OUT = sw*h_self + sum_e w_e * h_src
__global__ __launch_bounds__(256) void node_agg(
    const unsigned short* __restrict__ Hb, const int* __restrict__ offsets,
    const int2* __restrict__ edata, const float* __restrict__ sw,
    float* __restrict__ OUT)
{
  const int wid = (blockIdx.x * blockDim.x + threadIdx.x) >> 6;
  if (wid >= N_NODES) return;
  const int lane = threadIdx.x & 63;
  const int e0 = offsets[wid];
  const int e1 = offsets[wid + 1];

  float a0 = 0.f, a1 = 0.f, a2 = 0.f, a3 = 0.f;

  for (int base = e0; base < e1; base += 64) {
    const int avail = e1 - base;
    int2 d = make_int2(0, 0);
    if (lane < avail) d = edata[base + lane];
    const int n = (avail < 64) ? avail : 64;
    int j = 0;
    for (; j + 4 <= n; j += 4) {
      const int   s0 = __shfl(d.x, j, 64),     s1 = __shfl(d.x, j + 1, 64);
      const int   s2 = __shfl(d.x, j + 2, 64), s3 = __shfl(d.x, j + 3, 64);
      const float w0 = __int_as_float(__shfl(d.y, j, 64));
      const float w1 = __int_as_float(__shfl(d.y, j + 1, 64));
      const float w2 = __int_as_float(__shfl(d.y, j + 2, 64));
      const float w3 = __int_as_float(__shfl(d.y, j + 3, 64));
      const ushort4 h0 = *(const ushort4*)(Hb + (size_t)s0 * OUT_CH + lane * 4);
      const ushort4 h1 = *(const ushort4*)(Hb + (size_t)s1 * OUT_CH + lane * 4);
      const ushort4 h2 = *(const ushort4*)(Hb + (size_t)s2 * OUT_CH + lane * 4);
      const ushort4 h3 = *(const ushort4*)(Hb + (size_t)s3 * OUT_CH + lane * 4);
      a0 += w0 * bf2f(h0.x) + w1 * bf2f(h1.x) + w2 * bf2f(h2.x) + w3 * bf2f(h3.x);
      a1 += w0 * bf2f(h0.y) + w1 * bf2f(h1.y) + w2 * bf2f(h2.y) + w3 * bf2f(h3.y);
      a2 += w0 * bf2f(h0.z) + w1 * bf2f(h1.z) + w2 * bf2f(h2.z) + w3 * bf2f(h3.z);
      a3 += w0 * bf2f(h0.w) + w1 * bf2f(h1.w) + w2 * bf2f(h2.w) + w3 * bf2f(h3.w);
    }
    for (; j < n; j++) {
      const int   s = __shfl(d.x, j, 64);
      const float wgt = __int_as_float(__shfl(d.y, j, 64));
      const ushort4 h = *(const ushort4*)(Hb + (size_t)s * OUT_CH + lane * 4);
      a0 += wgt * bf2f(h.x); a1 += wgt * bf2f(h.y);
      a2 += wgt * bf2f(h.z); a3 += wgt * bf2f(h.w);
    }
  }

  const float swv = sw[wid];
  const ushort4 hs = *(const ushort4*)(Hb + (size_t)wid * OUT_CH + lane * 4);
  float4 o;
  o.x = a0 + swv * bf2f(hs.x);
  o.y = a1 + swv * bf2f(hs.y);
  o.z = a2 + swv * bf2f(hs.z);
  o.w = a3 + swv * bf2f(hs.w);
  *(float4*)(OUT + (size_t)wid * OUT_CH + lane * 4) = o;
}

extern "C" void kernel_launch(void* const* d_in, const int* in_sizes, int n_in,
                              void* d_out, int out_size, void* d_ws, size_t ws_size,
                              hipStream_t stream) {
  const float* x   = (const float*)d_in[0];
  const float* W   = (const float*)d_in[1];
  const float* b   = (const float*)d_in[2];
  const int*   src = (const int*)d_in[3];
  const int*   tar = (const int*)d_in[4];
  const float* ew  = (const float*)d_in[5];
  const float* sw  = (const float*)d_in[6];
  float* out = (float*)d_out;

  // ws: Wb 0.5MB | Hb 25.6MB | counts | offsets | cursor | blocksum | edata 6.4MB  (~33MB)
  char* ws = (char*)d_ws;
  size_t o = 0;
  unsigned short* Wb = (unsigned short*)(ws + o);
  o += (size_t)OUT_CH * IN_CH * 2;          o = (o + 255) & ~(size_t)255;
  unsigned short* Hb = (unsigned short*)(ws + o);
  o += (size_t)N_NODES * OUT_CH * 2;        o = (o + 255) & ~(size_t)255;
  int* counts   = (int*)(ws + o); o += (size_t)N_NODES * 4;       o = (o + 255) & ~(size_t)255;
  int* offsets  = (int*)(ws + o); o += (size_t)(N_NODES + 1) * 4; o = (o + 255) & ~(size_t)255;
  int* cursor   = (int*)(ws + o); o += (size_t)N_NODES * 4;       o = (o + 255) & ~(size_t)255;
  int* blocksum = (int*)(ws + o); o += (size_t)NBLK * 4;          o = (o + 255) & ~(size_t)255;
  int2* edata   = (int2*)(ws + o);

  hipMemsetAsync(counts, 0, (size_t)N_NODES * 4, stream);
  prep_hist<<<256 + (N_EDGES + 255) / 256, 256, 0, stream>>>(W, Wb, tar, counts);
  scan_block<<<NBLK, 256, 0, stream>>>(counts, offsets, blocksum);
  scan_sums<<<1, 256, 0, stream>>>(blocksum, offsets);
  finalize_offsets<<<NBLK, 256, 0, stream>>>(offsets, blocksum, cursor);
  fill_csr<<<(N_EDGES + 255) / 256, 256, 0, stream>>>(src, tar, ew, cursor, edata);

  dim3 g1((N_NODES + 127) / 128, OUT_CH / 64);
  gemm_proj<<<g1, 256, 0, stream>>>(x, Wb, b, Hb);

  const long long nthreads = (long long)N_NODES * 64;
  node_agg<<<(int)((nthreads + 255) / 256), 256, 0, stream>>>(Hb, offsets, edata, sw, out);
}

// Round 10
// 397.569 us; speedup vs baseline: 1.4269x; 1.4269x over previous
//
#include <hip/hip_runtime.h>
#include <hip/hip_bf16.h>

#define N_NODES 50000
#define N_EDGES 800000
#define IN_CH 1024
#define OUT_CH 256
#define NBLK 196  // ceil(N_NODES/256)

typedef __attribute__((ext_vector_type(8))) short bf16x8;
typedef __attribute__((ext_vector_type(4))) float f32x4;

__device__ inline unsigned short f2bf(float f) {
  union { float f; unsigned int u; } v; v.f = f;
  unsigned int r = v.u + 0x7fffu + ((v.u >> 16) & 1u);
  return (unsigned short)(r >> 16);
}
__device__ inline float bf2f(unsigned short u) {
  union { unsigned int u; float f; } v; v.u = ((unsigned int)u) << 16;
  return v.f;
}
// pack two f32 -> two bf16 in one u32 (lo = a, hi = b), RNE
__device__ inline unsigned int cvtpk_bf16(float a, float b) {
  unsigned int r;
  asm("v_cvt_pk_bf16_f32 %0, %1, %2" : "=v"(r) : "v"(a), "v"(b));
  return r;
}

// blocks [0,256): convert W fp32 -> bf16; blocks [256,...): histogram of tar
__global__ __launch_bounds__(256) void prep_hist(const float* __restrict__ W,
                                                 unsigned short* __restrict__ Wb,
                                                 const int* __restrict__ tar,
                                                 int* __restrict__ counts) {
  const int b = blockIdx.x, t = threadIdx.x;
  if (b < 256) {
    const int i4 = (b * 256 + t) * 4;
    float4 f = *(const float4*)(W + i4);
    *(ushort4*)(Wb + i4) = make_ushort4(f2bf(f.x), f2bf(f.y), f2bf(f.z), f2bf(f.w));
  } else {
    const int e = (b - 256) * 256 + t;
    if (e < N_EDGES) atomicAdd(&counts[tar[e]], 1);
  }
}

// Hb[m][n] = bf16( sum_k X[m][k]*W[n][k] + b[n] )
// Round-4 template with BK=64 (16 K-steps, half the barriers) and round-7's
// verified XOR-chunk swizzle (phys_chunk = c ^ (row&7); read key l15&7 == row&7).
// 64x128 tile, 4 waves (2x2), wave tile 32x64; depth-2 register prefetch,
// double-buffered LDS (48KB -> 3 blocks/CU), plain __syncthreads.
__global__ __launch_bounds__(256, 3) void gemm_proj(
    const float* __restrict__ X, const unsigned short* __restrict__ Wb,
    const float* __restrict__ bias, unsigned short* __restrict__ Hb)
{
  __shared__ unsigned short lds_a[2][64][64];    // 16 KB
  __shared__ unsigned short lds_b[2][128][64];   // 32 KB

  const int tid  = threadIdx.x;
  const int lane = tid & 63;
  const int w    = tid >> 6;
  const int wr   = w >> 1, wc = w & 1;
  const int gm0  = blockIdx.x * 64;
  const int gn0  = blockIdx.y * 128;
  const int l15  = lane & 15;
  const int hi   = lane >> 4;

  // A staging: 4 thr/row, chunks {ac0, ac0+1} (chunk = 8 bf16 = 8 fp32 = 32B glb)
  const int ar  = tid >> 2;            // 0..63
  const int ac0 = (tid & 3) * 2;       // 0,2,4,6
  // B staging: 2 thr/row, chunks {bc0..bc0+3}
  const int br  = tid >> 1;            // 0..127
  const int bc0 = (tid & 1) * 4;       // 0,4

  const int  arow = gm0 + ar;
  const bool aok  = arow < N_NODES;
  const float* xp = X + (size_t)arow * IN_CH;
  const unsigned short* wp = Wb + (size_t)(gn0 + br) * IN_CH;
  const float4 fz = make_float4(0.f, 0.f, 0.f, 0.f);

  f32x4 acc[2][4];
  #pragma unroll
  for (int i = 0; i < 2; i++)
    #pragma unroll
    for (int j = 0; j < 4; j++) acc[i][j] = (f32x4)0.0f;

  float4 pa[2][4];   // [set][4 float4] = chunks ac0 (f4 0,1) and ac0+1 (f4 2,3)
  bf16x8 pbv[2][4];  // [set][q] = chunk bc0+q

#define LOADR(KS, S)                                                           \
  {                                                                            \
    const int k0_ = (KS) * 64;                                                 \
    const float* xa_ = xp + k0_ + ac0 * 8;                                     \
    pa[S][0] = aok ? *(const float4*)(xa_)      : fz;                          \
    pa[S][1] = aok ? *(const float4*)(xa_ + 4)  : fz;                          \
    pa[S][2] = aok ? *(const float4*)(xa_ + 8)  : fz;                          \
    pa[S][3] = aok ? *(const float4*)(xa_ + 12) : fz;                          \
    const unsigned short* wb_ = wp + k0_ + bc0 * 8;                            \
    pbv[S][0] = *(const bf16x8*)(wb_);                                         \
    pbv[S][1] = *(const bf16x8*)(wb_ + 8);                                     \
    pbv[S][2] = *(const bf16x8*)(wb_ + 16);                                    \
    pbv[S][3] = *(const bf16x8*)(wb_ + 24);                                    \
  }

#define WRITER(BUF, S)                                                         \
  {                                                                            \
    const int pc0_ = ac0 ^ (ar & 7);                                           \
    const int pc1_ = (ac0 + 1) ^ (ar & 7);                                     \
    union { unsigned int u[4]; bf16x8 v; } ta_;                                \
    ta_.u[0] = cvtpk_bf16(pa[S][0].x, pa[S][0].y);                             \
    ta_.u[1] = cvtpk_bf16(pa[S][0].z, pa[S][0].w);                             \
    ta_.u[2] = cvtpk_bf16(pa[S][1].x, pa[S][1].y);                             \
    ta_.u[3] = cvtpk_bf16(pa[S][1].z, pa[S][1].w);                             \
    *(bf16x8*)&lds_a[BUF][ar][pc0_ * 8] = ta_.v;                               \
    ta_.u[0] = cvtpk_bf16(pa[S][2].x, pa[S][2].y);                             \
    ta_.u[1] = cvtpk_bf16(pa[S][2].z, pa[S][2].w);                             \
    ta_.u[2] = cvtpk_bf16(pa[S][3].x, pa[S][3].y);                             \
    ta_.u[3] = cvtpk_bf16(pa[S][3].z, pa[S][3].w);                             \
    *(bf16x8*)&lds_a[BUF][ar][pc1_ * 8] = ta_.v;                               \
    _Pragma("unroll")                                                          \
    for (int q = 0; q < 4; q++) {                                              \
      const int pcb_ = (bc0 + q) ^ (br & 7);                                   \
      *(bf16x8*)&lds_b[BUF][br][pcb_ * 8] = pbv[S][q];                         \
    }                                                                          \
  }

  // one BK=64 step = two K=32 sub-steps; chunk c = kk2*4 + hi; phys = c^(l15&7)
#define COMPUTE(BUF)                                                           \
  {                                                                            \
    _Pragma("unroll")                                                          \
    for (int kk2 = 0; kk2 < 2; kk2++) {                                        \
      const int pc_ = ((kk2 << 2) + hi) ^ (l15 & 7);                           \
      bf16x8 a0 = *(const bf16x8*)&lds_a[BUF][wr * 32 + l15][pc_ * 8];         \
      bf16x8 a1 = *(const bf16x8*)&lds_a[BUF][wr * 32 + 16 + l15][pc_ * 8];    \
      bf16x8 b0 = *(const bf16x8*)&lds_b[BUF][wc * 64 + l15][pc_ * 8];         \
      bf16x8 b1 = *(const bf16x8*)&lds_b[BUF][wc * 64 + 16 + l15][pc_ * 8];    \
      bf16x8 b2 = *(const bf16x8*)&lds_b[BUF][wc * 64 + 32 + l15][pc_ * 8];    \
      bf16x8 b3 = *(const bf16x8*)&lds_b[BUF][wc * 64 + 48 + l15][pc_ * 8];    \
      acc[0][0] = __builtin_amdgcn_mfma_f32_16x16x32_bf16(a0, b0, acc[0][0], 0, 0, 0); \
      acc[0][1] = __builtin_amdgcn_mfma_f32_16x16x32_bf16(a0, b1, acc[0][1], 0, 0, 0); \
      acc[0][2] = __builtin_amdgcn_mfma_f32_16x16x32_bf16(a0, b2, acc[0][2], 0, 0, 0); \
      acc[0][3] = __builtin_amdgcn_mfma_f32_16x16x32_bf16(a0, b3, acc[0][3], 0, 0, 0); \
      acc[1][0] = __builtin_amdgcn_mfma_f32_16x16x32_bf16(a1, b0, acc[1][0], 0, 0, 0); \
      acc[1][1] = __builtin_amdgcn_mfma_f32_16x16x32_bf16(a1, b1, acc[1][1], 0, 0, 0); \
      acc[1][2] = __builtin_amdgcn_mfma_f32_16x16x32_bf16(a1, b2, acc[1][2], 0, 0, 0); \
      acc[1][3] = __builtin_amdgcn_mfma_f32_16x16x32_bf16(a1, b3, acc[1][3], 0, 0, 0); \
    }                                                                          \
  }

  // prologue: step0 -> buf0 (written), step1 -> regs set 1
  LOADR(0, 0);
  WRITER(0, 0);
  LOADR(1, 1);
  __syncthreads();

  for (int ks = 0; ks < 16; ks += 2) {
    if (ks + 2 < 16) LOADR(ks + 2, 0);
    COMPUTE(0);
    WRITER(1, 1);
    __syncthreads();
    if (ks + 3 < 16) LOADR(ks + 3, 1);
    COMPUTE(1);
    if (ks + 2 < 16) WRITER(0, 0);
    __syncthreads();
  }
#undef LOADR
#undef WRITER
#undef COMPUTE

  // epilogue: C/D layout col = lane&15, row = (lane>>4)*4 + r
  float bj[4];
  #pragma unroll
  for (int j = 0; j < 4; j++)
    bj[j] = bias[gn0 + wc * 64 + j * 16 + l15];

  #pragma unroll
  for (int i = 0; i < 2; i++) {
    const int grow_base = gm0 + wr * 32 + i * 16 + hi * 4;
    #pragma unroll
    for (int r = 0; r < 4; r++) {
      const int grow = grow_base + r;
      if (grow < N_NODES) {
        #pragma unroll
        for (int j = 0; j < 4; j++) {
          const int gcol = gn0 + wc * 64 + j * 16 + l15;
          Hb[(size_t)grow * OUT_CH + gcol] = f2bf(acc[i][j][r] + bj[j]);
        }
      }
    }
  }
}

// per-block exclusive scan; local-excl to offsets, block total to blocksum
__global__ __launch_bounds__(256) void scan_block(const int* __restrict__ counts,
                                                  int* __restrict__ offsets,
                                                  int* __restrict__ blocksum) {
  __shared__ int wsum[4];
  const int tid = threadIdx.x, lane = tid & 63, wv = tid >> 6;
  const int i = blockIdx.x * 256 + tid;
  const int v = (i < N_NODES) ? counts[i] : 0;
  int s = v;
  #pragma unroll
  for (int off = 1; off < 64; off <<= 1) {
    int t = __shfl_up(s, off, 64);
    if (lane >= off) s += t;
  }
  if (lane == 63) wsum[wv] = s;
  __syncthreads();
  if (tid == 0) {
    int c = 0;
    #pragma unroll
    for (int k = 0; k < 4; k++) { int t = wsum[k]; wsum[k] = c; c += t; }
  }
  __syncthreads();
  const int excl = wsum[wv] + s - v;
  if (i < N_NODES) offsets[i] = excl;
  if (tid == 255) blocksum[blockIdx.x] = excl + v;
}

__global__ __launch_bounds__(256) void scan_sums(int* __restrict__ blocksum,
                                                 int* __restrict__ offsets) {
  __shared__ int wsum[4];
  const int tid = threadIdx.x, lane = tid & 63, wv = tid >> 6;
  const int v = (tid < NBLK) ? blocksum[tid] : 0;
  int s = v;
  #pragma unroll
  for (int off = 1; off < 64; off <<= 1) {
    int t = __shfl_up(s, off, 64);
    if (lane >= off) s += t;
  }
  if (lane == 63) wsum[wv] = s;
  __syncthreads();
  if (tid == 0) {
    int c = 0;
    #pragma unroll
    for (int k = 0; k < 4; k++) { int t = wsum[k]; wsum[k] = c; c += t; }
  }
  __syncthreads();
  const int excl = wsum[wv] + s - v;
  if (tid < NBLK) blocksum[tid] = excl;
  if (tid == 255) offsets[N_NODES] = excl;
}

__global__ __launch_bounds__(256) void finalize_offsets(int* __restrict__ offsets,
                                                        const int* __restrict__ blocksum,
                                                        int* __restrict__ cursor) {
  const int i = blockIdx.x * 256 + threadIdx.x;
  if (i < N_NODES) {
    const int off = offsets[i] + blocksum[i >> 8];
    offsets[i] = off;
    cursor[i] = off;
  }
}

__global__ __launch_bounds__(256) void fill_csr(const int* __restrict__ src,
                                                const int* __restrict__ tar,
                                                const float* __restrict__ ew,
                                                int* __restrict__ cursor,
                                                int2* __restrict__ edata) {
  int e = blockIdx.x * blockDim.x + threadIdx.x;
  if (e >= N_EDGES) return;
  const int t = tar[e];
  const int p = atomicAdd(&cursor[t], 1);
  edata[p] = make_int2(src[e], __float_as_int(ew[e]));
}

// one wave per node: OUT = sw*h_self + sum_e w_e * h_src (8 gathers in flight)
__global__ __launch_bounds__(256) void node_agg(
    const unsigned short* __restrict__ Hb, const int* __restrict__ offsets,
    const int2* __restrict__ edata, const float* __restrict__ sw,
    float* __restrict__ OUT)
{
  const int wid = (blockIdx.x * blockDim.x + threadIdx.x) >> 6;
  if (wid >= N_NODES) return;
  const int lane = threadIdx.x & 63;
  const int e0 = offsets[wid];
  const int e1 = offsets[wid + 1];

  float a0 = 0.f, a1 = 0.f, a2 = 0.f, a3 = 0.f;

  for (int base = e0; base < e1; base += 64) {
    const int avail = e1 - base;
    int2 d = make_int2(0, 0);
    if (lane < avail) d = edata[base + lane];
    const int n = (avail < 64) ? avail : 64;
    int j = 0;
    for (; j + 8 <= n; j += 8) {
      int   sE[8];
      float wE[8];
      #pragma unroll
      for (int q = 0; q < 8; q++) {
        sE[q] = __shfl(d.x, j + q, 64);
        wE[q] = __int_as_float(__shfl(d.y, j + q, 64));
      }
      ushort4 hE[8];
      #pragma unroll
      for (int q = 0; q < 8; q++)
        hE[q] = *(const ushort4*)(Hb + (size_t)sE[q] * OUT_CH + lane * 4);
      #pragma unroll
      for (int q = 0; q < 8; q++) {
        a0 += wE[q] * bf2f(hE[q].x);
        a1 += wE[q] * bf2f(hE[q].y);
        a2 += wE[q] * bf2f(hE[q].z);
        a3 += wE[q] * bf2f(hE[q].w);
      }
    }
    for (; j < n; j++) {
      const int   s = __shfl(d.x, j, 64);
      const float wgt = __int_as_float(__shfl(d.y, j, 64));
      const ushort4 h = *(const ushort4*)(Hb + (size_t)s * OUT_CH + lane * 4);
      a0 += wgt * bf2f(h.x); a1 += wgt * bf2f(h.y);
      a2 += wgt * bf2f(h.z); a3 += wgt * bf2f(h.w);
    }
  }

  const float swv = sw[wid];
  const ushort4 hs = *(const ushort4*)(Hb + (size_t)wid * OUT_CH + lane * 4);
  float4 o;
  o.x = a0 + swv * bf2f(hs.x);
  o.y = a1 + swv * bf2f(hs.y);
  o.z = a2 + swv * bf2f(hs.z);
  o.w = a3 + swv * bf2f(hs.w);
  *(float4*)(OUT + (size_t)wid * OUT_CH + lane * 4) = o;
}

extern "C" void kernel_launch(void* const* d_in, const int* in_sizes, int n_in,
                              void* d_out, int out_size, void* d_ws, size_t ws_size,
                              hipStream_t stream) {
  const float* x   = (const float*)d_in[0];
  const float* W   = (const float*)d_in[1];
  const float* b   = (const float*)d_in[2];
  const int*   src = (const int*)d_in[3];
  const int*   tar = (const int*)d_in[4];
  const float* ew  = (const float*)d_in[5];
  const float* sw  = (const float*)d_in[6];
  float* out = (float*)d_out;

  // ws: Wb 0.5MB | Hb 25.6MB | counts | offsets | cursor | blocksum | edata 6.4MB  (~33MB)
  char* ws = (char*)d_ws;
  size_t o = 0;
  unsigned short* Wb = (unsigned short*)(ws + o);
  o += (size_t)OUT_CH * IN_CH * 2;          o = (o + 255) & ~(size_t)255;
  unsigned short* Hb = (unsigned short*)(ws + o);
  o += (size_t)N_NODES * OUT_CH * 2;        o = (o + 255) & ~(size_t)255;
  int* counts   = (int*)(ws + o); o += (size_t)N_NODES * 4;       o = (o + 255) & ~(size_t)255;
  int* offsets  = (int*)(ws + o); o += (size_t)(N_NODES + 1) * 4; o = (o + 255) & ~(size_t)255;
  int* cursor   = (int*)(ws + o); o += (size_t)N_NODES * 4;       o = (o + 255) & ~(size_t)255;
  int* blocksum = (int*)(ws + o); o += (size_t)NBLK * 4;          o = (o + 255) & ~(size_t)255;
  int2* edata   = (int2*)(ws + o);

  hipMemsetAsync(counts, 0, (size_t)N_NODES * 4, stream);
  prep_hist<<<256 + (N_EDGES + 255) / 256, 256, 0, stream>>>(W, Wb, tar, counts);
  scan_block<<<NBLK, 256, 0, stream>>>(counts, offsets, blocksum);
  scan_sums<<<1, 256, 0, stream>>>(blocksum, offsets);
  finalize_offsets<<<NBLK, 256, 0, stream>>>(offsets, blocksum, cursor);
  fill_csr<<<(N_EDGES + 255) / 256, 256, 0, stream>>>(src, tar, ew, cursor, edata);

  dim3 g1((N_NODES + 63) / 64, OUT_CH / 128);
  gemm_proj<<<g1, 256, 0, stream>>>(x, Wb, b, Hb);

  const long long nthreads = (long long)N_NODES * 64;
  node_agg<<<(int)((nthreads + 255) / 256), 256, 0, stream>>>(Hb, offsets, edata, sw, out);
}

// Round 11
// 236.339 us; speedup vs baseline: 2.4003x; 1.6822x over previous
//
#include <hip/hip_runtime.h>
#include <hip/hip_bf16.h>

#define N_NODES 50000
#define N_EDGES 800000
#define IN_CH 1024
#define OUT_CH 256
#define NBLK 196  // ceil(N_NODES/256)

typedef __attribute__((ext_vector_type(8))) short bf16x8;
typedef __attribute__((ext_vector_type(4))) float f32x4;

__device__ inline unsigned short f2bf(float f) {
  union { float f; unsigned int u; } v; v.f = f;
  unsigned int r = v.u + 0x7fffu + ((v.u >> 16) & 1u);
  return (unsigned short)(r >> 16);
}
__device__ inline float bf2f(unsigned short u) {
  union { unsigned int u; float f; } v; v.u = ((unsigned int)u) << 16;
  return v.f;
}
// pack two f32 -> two bf16 in one u32 (lo = a, hi = b), RNE
__device__ inline unsigned int cvtpk_bf16(float a, float b) {
  unsigned int r;
  asm("v_cvt_pk_bf16_f32 %0, %1, %2" : "=v"(r) : "v"(a), "v"(b));
  return r;
}

// async global->LDS, 16B per lane; LDS dest is wave-uniform base + lane*16
#define GLOAD16(SRC, DST)                                                      \
  __builtin_amdgcn_global_load_lds(                                            \
      (const __attribute__((address_space(1))) void*)(SRC),                    \
      (__attribute__((address_space(3))) void*)(DST), 16, 0, 0)

// counted-vmcnt barrier (T4): force all but the newest STAGE's 6 wave-loads
// to complete; loads for the tile-after-next stay in flight across the barrier.
__device__ inline void waitbar6() {
  __builtin_amdgcn_sched_barrier(0);
  asm volatile("s_waitcnt vmcnt(6)" ::: "memory");
  __builtin_amdgcn_s_barrier();
  __builtin_amdgcn_sched_barrier(0);
}
__device__ inline void waitbar0() {
  __builtin_amdgcn_sched_barrier(0);
  asm volatile("s_waitcnt vmcnt(0)" ::: "memory");
  __builtin_amdgcn_s_barrier();
  __builtin_amdgcn_sched_barrier(0);
}

// blocks [0,256): convert W fp32 -> bf16; blocks [256,...): histogram of tar
__global__ __launch_bounds__(256) void prep_hist(const float* __restrict__ W,
                                                 unsigned short* __restrict__ Wb,
                                                 const int* __restrict__ tar,
                                                 int* __restrict__ counts) {
  const int b = blockIdx.x, t = threadIdx.x;
  if (b < 256) {
    const int i4 = (b * 256 + t) * 4;
    float4 f = *(const float4*)(W + i4);
    *(ushort4*)(Wb + i4) = make_ushort4(f2bf(f.x), f2bf(f.y), f2bf(f.z), f2bf(f.w));
  } else {
    const int e = (b - 256) * 256 + t;
    if (e < N_EDGES) atomicAdd(&counts[tar[e]], 1);
  }
}

// Hb[m][n] = bf16( sum_k X[m][k]*W[n][k] + b[n] )
// Round-7 STAGE/COMPUTE (verified) + 3-buffer counted-vmcnt pipeline (T3+T4):
// 128x128 tile, BK=32, grid (391,2). A fp32 in LDS (cvt at read), B bf16.
// 72KB LDS -> 2 blocks/CU; vmcnt never drains to 0 in steady state, so
// ~2 STAGEs (12 wave-loads, 12KB/wave) stay in flight continuously.
__global__ __launch_bounds__(256, 2) void gemm_proj(
    const float* __restrict__ X, const unsigned short* __restrict__ Wb,
    const float* __restrict__ bias, unsigned short* __restrict__ Hb)
{
  __shared__ float lds_a[3][128][32];           // 48 KB (fp32 A tiles)
  __shared__ unsigned short lds_b[3][128][32];  // 24 KB (bf16 B tiles)

  const int tid  = threadIdx.x;
  const int lane = tid & 63;
  const int w    = tid >> 6;
  const int wr   = w >> 1, wc = w & 1;
  const int gm0  = blockIdx.x * 128;
  const int gn0  = blockIdx.y * 128;

  f32x4 acc[4][4];
  #pragma unroll
  for (int i = 0; i < 4; i++)
    #pragma unroll
    for (int j = 0; j < 4; j++) acc[i][j] = (f32x4)0.0f;

  // A: 16 wave-loads of 1KB (8 rows x 128B); wave w does wl = 4w..4w+3.
  //    OOB rows CLAMPED (not skipped) so every wave issues exactly 6 loads
  //    per STAGE -> the literal vmcnt(6) count stays correct for all blocks.
  // B: 8 wave-loads (16 rows x 64B); wl = 2w..2w+1.
  // XOR-swizzled SOURCE chunk + linear dest; read back at chunk c^(row&7).
#define STAGE(BUF, K0)                                                         \
  {                                                                            \
    _Pragma("unroll")                                                          \
    for (int q = 0; q < 4; q++) {                                              \
      const int wl  = w * 4 + q;                                               \
      const int row = 8 * wl + (lane >> 3);                                    \
      int grow = gm0 + row;                                                    \
      if (grow > N_NODES - 1) grow = N_NODES - 1;                              \
      const int sc = (lane & 7) ^ (row & 7);                                   \
      GLOAD16(X + (size_t)grow * IN_CH + (K0) + sc * 4,                        \
              &lds_a[BUF][8 * wl][0]);                                         \
    }                                                                          \
    _Pragma("unroll")                                                          \
    for (int q = 0; q < 2; q++) {                                              \
      const int wl  = w * 2 + q;                                               \
      const int row = 16 * wl + (lane >> 2);                                   \
      const int sc  = (lane & 3) ^ (row & 3);                                  \
      GLOAD16(Wb + (size_t)(gn0 + row) * IN_CH + (K0) + sc * 8,                \
              &lds_b[BUF][16 * wl][0]);                                        \
    }                                                                          \
  }

#define COMPUTE(BUF)                                                           \
  {                                                                            \
    const int l15 = lane & 15;                                                 \
    const int kb  = lane >> 4;                                                 \
    bf16x8 af[4], bfr[4];                                                      \
    _Pragma("unroll")                                                          \
    for (int i = 0; i < 4; i++) {                                              \
      const int row = wr * 64 + i * 16 + l15;                                  \
      const int c0  = (2 * kb) ^ (row & 7);                                    \
      const int c1  = (2 * kb + 1) ^ (row & 7);                                \
      f32x4 lo = *(const f32x4*)&lds_a[BUF][row][c0 * 4];                      \
      f32x4 hi = *(const f32x4*)&lds_a[BUF][row][c1 * 4];                      \
      union { unsigned int u[4]; bf16x8 v; } t;                                \
      t.u[0] = cvtpk_bf16(lo[0], lo[1]);                                       \
      t.u[1] = cvtpk_bf16(lo[2], lo[3]);                                       \
      t.u[2] = cvtpk_bf16(hi[0], hi[1]);                                       \
      t.u[3] = cvtpk_bf16(hi[2], hi[3]);                                       \
      af[i] = t.v;                                                             \
    }                                                                          \
    _Pragma("unroll")                                                          \
    for (int j = 0; j < 4; j++) {                                              \
      const int row = wc * 64 + j * 16 + l15;                                  \
      const int c   = kb ^ (row & 3);                                          \
      bfr[j] = *(const bf16x8*)&lds_b[BUF][row][c * 8];                        \
    }                                                                          \
    _Pragma("unroll")                                                          \
    for (int i = 0; i < 4; i++)                                                \
      _Pragma("unroll")                                                        \
      for (int j = 0; j < 4; j++)                                              \
        acc[i][j] = __builtin_amdgcn_mfma_f32_16x16x32_bf16(af[i], bfr[j],     \
                                                            acc[i][j], 0, 0, 0); \
  }

  // prologue: tiles 0 and 1 in flight; wait tile 0 only (vmcnt(6))
  STAGE(0, 0);
  STAGE(1, 32);
  waitbar6();

  // steady state: iter t computes buf[t%3]; issues STAGE(t+2) into
  // buf[(t+2)%3] (last read at iter t-1, behind the barrier); end-of-iter
  // vmcnt(6) forces STAGE(t+1) complete, leaves STAGE(t+2) in flight.
  #pragma unroll
  for (int t = 0; t < 32; t++) {
    if (t + 2 < 32) STAGE((t + 2) % 3, (t + 2) * 32);
    COMPUTE(t % 3);
    if (t + 2 < 32)      waitbar6();
    else if (t == 30)    waitbar0();   // drain once: STAGE(31) done
    // t == 31: fall through to epilogue
  }
#undef STAGE
#undef COMPUTE

  // epilogue: C/D layout col = lane&15, row = (lane>>4)*4 + r
  float bj[4];
  #pragma unroll
  for (int j = 0; j < 4; j++)
    bj[j] = bias[gn0 + wc * 64 + j * 16 + (lane & 15)];

  #pragma unroll
  for (int i = 0; i < 4; i++) {
    const int grow_base = gm0 + wr * 64 + i * 16 + ((lane >> 4) << 2);
    #pragma unroll
    for (int r = 0; r < 4; r++) {
      const int grow = grow_base + r;
      if (grow < N_NODES) {
        #pragma unroll
        for (int j = 0; j < 4; j++) {
          const int gcol = gn0 + wc * 64 + j * 16 + (lane & 15);
          Hb[(size_t)grow * OUT_CH + gcol] = f2bf(acc[i][j][r] + bj[j]);
        }
      }
    }
  }
}

// per-block exclusive scan; local-excl to offsets, block total to blocksum
__global__ __launch_bounds__(256) void scan_block(const int* __restrict__ counts,
                                                  int* __restrict__ offsets,
                                                  int* __restrict__ blocksum) {
  __shared__ int wsum[4];
  const int tid = threadIdx.x, lane = tid & 63, wv = tid >> 6;
  const int i = blockIdx.x * 256 + tid;
  const int v = (i < N_NODES) ? counts[i] : 0;
  int s = v;
  #pragma unroll
  for (int off = 1; off < 64; off <<= 1) {
    int t = __shfl_up(s, off, 64);
    if (lane >= off) s += t;
  }
  if (lane == 63) wsum[wv] = s;
  __syncthreads();
  if (tid == 0) {
    int c = 0;
    #pragma unroll
    for (int k = 0; k < 4; k++) { int t = wsum[k]; wsum[k] = c; c += t; }
  }
  __syncthreads();
  const int excl = wsum[wv] + s - v;
  if (i < N_NODES) offsets[i] = excl;
  if (tid == 255) blocksum[blockIdx.x] = excl + v;
}

__global__ __launch_bounds__(256) void scan_sums(int* __restrict__ blocksum,
                                                 int* __restrict__ offsets) {
  __shared__ int wsum[4];
  const int tid = threadIdx.x, lane = tid & 63, wv = tid >> 6;
  const int v = (tid < NBLK) ? blocksum[tid] : 0;
  int s = v;
  #pragma unroll
  for (int off = 1; off < 64; off <<= 1) {
    int t = __shfl_up(s, off, 64);
    if (lane >= off) s += t;
  }
  if (lane == 63) wsum[wv] = s;
  __syncthreads();
  if (tid == 0) {
    int c = 0;
    #pragma unroll
    for (int k = 0; k < 4; k++) { int t = wsum[k]; wsum[k] = c; c += t; }
  }
  __syncthreads();
  const int excl = wsum[wv] + s - v;
  if (tid < NBLK) blocksum[tid] = excl;
  if (tid == 255) offsets[N_NODES] = excl;
}

__global__ __launch_bounds__(256) void finalize_offsets(int* __restrict__ offsets,
                                                        const int* __restrict__ blocksum,
                                                        int* __restrict__ cursor) {
  const int i = blockIdx.x * 256 + threadIdx.x;
  if (i < N_NODES) {
    const int off = offsets[i] + blocksum[i >> 8];
    offsets[i] = off;
    cursor[i] = off;
  }
}

__global__ __launch_bounds__(256) void fill_csr(const int* __restrict__ src,
                                                const int* __restrict__ tar,
                                                const float* __restrict__ ew,
                                                int* __restrict__ cursor,
                                                int2* __restrict__ edata) {
  int e = blockIdx.x * blockDim.x + threadIdx.x;
  if (e >= N_EDGES) return;
  const int t = tar[e];
  const int p = atomicAdd(&cursor[t], 1);
  edata[p] = make_int2(src[e], __float_as_int(ew[e]));
}

// one wave per node: OUT = sw*h_self + sum_e w_e * h_src (8 gathers in flight)
__global__ __launch_bounds__(256) void node_agg(
    const unsigned short* __restrict__ Hb, const int* __restrict__ offsets,
    const int2* __restrict__ edata, const float* __restrict__ sw,
    float* __restrict__ OUT)
{
  const int wid = (blockIdx.x * blockDim.x + threadIdx.x) >> 6;
  if (wid >= N_NODES) return;
  const int lane = threadIdx.x & 63;
  const int e0 = offsets[wid];
  const int e1 = offsets[wid + 1];

  float a0 = 0.f, a1 = 0.f, a2 = 0.f, a3 = 0.f;

  for (int base = e0; base < e1; base += 64) {
    const int avail = e1 - base;
    int2 d = make_int2(0, 0);
    if (lane < avail) d = edata[base + lane];
    const int n = (avail < 64) ? avail : 64;
    int j = 0;
    for (; j + 8 <= n; j += 8) {
      int   sE[8];
      float wE[8];
      #pragma unroll
      for (int q = 0; q < 8; q++) {
        sE[q] = __shfl(d.x, j + q, 64);
        wE[q] = __int_as_float(__shfl(d.y, j + q, 64));
      }
      ushort4 hE[8];
      #pragma unroll
      for (int q = 0; q < 8; q++)
        hE[q] = *(const ushort4*)(Hb + (size_t)sE[q] * OUT_CH + lane * 4);
      #pragma unroll
      for (int q = 0; q < 8; q++) {
        a0 += wE[q] * bf2f(hE[q].x);
        a1 += wE[q] * bf2f(hE[q].y);
        a2 += wE[q] * bf2f(hE[q].z);
        a3 += wE[q] * bf2f(hE[q].w);
      }
    }
    for (; j < n; j++) {
      const int   s = __shfl(d.x, j, 64);
      const float wgt = __int_as_float(__shfl(d.y, j, 64));
      const ushort4 h = *(const ushort4*)(Hb + (size_t)s * OUT_CH + lane * 4);
      a0 += wgt * bf2f(h.x); a1 += wgt * bf2f(h.y);
      a2 += wgt * bf2f(h.z); a3 += wgt * bf2f(h.w);
    }
  }

  const float swv = sw[wid];
  const ushort4 hs = *(const ushort4*)(Hb + (size_t)wid * OUT_CH + lane * 4);
  float4 o;
  o.x = a0 + swv * bf2f(hs.x);
  o.y = a1 + swv * bf2f(hs.y);
  o.z = a2 + swv * bf2f(hs.z);
  o.w = a3 + swv * bf2f(hs.w);
  *(float4*)(OUT + (size_t)wid * OUT_CH + lane * 4) = o;
}

extern "C" void kernel_launch(void* const* d_in, const int* in_sizes, int n_in,
                              void* d_out, int out_size, void* d_ws, size_t ws_size,
                              hipStream_t stream) {
  const float* x   = (const float*)d_in[0];
  const float* W   = (const float*)d_in[1];
  const float* b   = (const float*)d_in[2];
  const int*   src = (const int*)d_in[3];
  const int*   tar = (const int*)d_in[4];
  const float* ew  = (const float*)d_in[5];
  const float* sw  = (const float*)d_in[6];
  float* out = (float*)d_out;

  // ws: Wb 0.5MB | Hb 25.6MB | counts | offsets | cursor | blocksum | edata 6.4MB  (~33MB)
  char* ws = (char*)d_ws;
  size_t o = 0;
  unsigned short* Wb = (unsigned short*)(ws + o);
  o += (size_t)OUT_CH * IN_CH * 2;          o = (o + 255) & ~(size_t)255;
  unsigned short* Hb = (unsigned short*)(ws + o);
  o += (size_t)N_NODES * OUT_CH * 2;        o = (o + 255) & ~(size_t)255;
  int* counts   = (int*)(ws + o); o += (size_t)N_NODES * 4;       o = (o + 255) & ~(size_t)255;
  int* offsets  = (int*)(ws + o); o += (size_t)(N_NODES + 1) * 4; o = (o + 255) & ~(size_t)255;
  int* cursor   = (int*)(ws + o); o += (size_t)N_NODES * 4;       o = (o + 255) & ~(size_t)255;
  int* blocksum = (int*)(ws + o); o += (size_t)NBLK * 4;          o = (o + 255) & ~(size_t)255;
  int2* edata   = (int2*)(ws + o);

  hipMemsetAsync(counts, 0, (size_t)N_NODES * 4, stream);
  prep_hist<<<256 + (N_EDGES + 255) / 256, 256, 0, stream>>>(W, Wb, tar, counts);
  scan_block<<<NBLK, 256, 0, stream>>>(counts, offsets, blocksum);
  scan_sums<<<1, 256, 0, stream>>>(blocksum, offsets);
  finalize_offsets<<<NBLK, 256, 0, stream>>>(offsets, blocksum, cursor);
  fill_csr<<<(N_EDGES + 255) / 256, 256, 0, stream>>>(src, tar, ew, cursor, edata);

  dim3 g1((N_NODES + 127) / 128, OUT_CH / 128);
  gemm_proj<<<g1, 256, 0, stream>>>(x, Wb, b, Hb);

  const long long nthreads = (long long)N_NODES * 64;
  node_agg<<<(int)((nthreads + 255) / 256), 256, 0, stream>>>(Hb, offsets, edata, sw, out);
}